// Round 5
// baseline (3163.433 us; speedup 1.0000x reference)
//
#include <hip/hip_runtime.h>

#define Bq 8
#define Tq 2048
#define Dq 512

typedef const __attribute__((address_space(1))) void* gas_t;
typedef __attribute__((address_space(3))) void* las_t;

// One wave: DMA 1KB (64 lanes x 16B) global -> LDS. Global addr per-lane,
// LDS base wave-uniform (HW adds lane*16). No VGPR round-trip, no reg defs.
__device__ __forceinline__ void dma1k(const float* g_lane, float* l_base) {
  __builtin_amdgcn_global_load_lds((gas_t)g_lane, (las_t)l_base, 16, 0, 0);
}

// DPP wave(64) sum, broadcast via readlane(63).
template <int CTRL>
__device__ __forceinline__ float dppadd(float v) {
  int r = __builtin_amdgcn_update_dpp(0, __float_as_int(v), CTRL, 0xF, 0xF, true);
  return v + __int_as_float(r);
}
__device__ __forceinline__ float wave_sum_bcast(float v) {
  v = dppadd<0x111>(v);  // row_shr:1
  v = dppadd<0x112>(v);  // row_shr:2
  v = dppadd<0x114>(v);  // row_shr:4
  v = dppadd<0x118>(v);  // row_shr:8
  v = dppadd<0x142>(v);  // row_bcast:15
  v = dppadd<0x143>(v);  // row_bcast:31
  return __int_as_float(__builtin_amdgcn_readlane(__float_as_int(v), 63));
}

// ---------------------------------------------------------------------------
// One scan step (4 waves, lockstep via one raw s_barrier per step).
// Invariant: the barrier inside step t publishes DMA'd rows <= t+3 for all
// streams (each wave waits vmcnt(6) on ITS stream: per-wave VMEM order/step is
// [DMA,DMA,...,store]; 6 younger ops = exactly through DMA of step t-2).
// Step t reads window rows rb..rb+4 (<= t+2) and pm/pg row t. Padded window
// entries (left/right edge) are masked: score forced to exact 0 (matching the
// reference's zero rows; they keep exp(0) in the softmax denominator) and
// prob contribution zeroed, so garbage ring slots are never observable.
// OSLOT: 4-deep output register rotation -> store-WAR waits are static no-ops.
// ---------------------------------------------------------------------------
template <int OSLOT>
__device__ __forceinline__ void sstep(
    int t, float m3, float m4, int lane, int ms, int based,
    const float* __restrict__ sb, float* __restrict__ po,
    float* __restrict__ ring, float (*red)[5][4],
    float2& st, float2& o0, float2& o1, float2& o2, float2& o3) {
  // A: DMA my stream's row t+5 into ring slot (row&7)
  int r5 = t + 5; if (r5 > Tq - 1) r5 = Tq - 1;
  {
    const float* g = sb + (size_t)r5 * Dq + lane * 4;
    float* l = ring + (size_t)(ms * 8 + (r5 & 7)) * Dq;
    dma1k(g, l);
    dma1k(g + 256, l + 256);
  }
  // B: ds_read my 2-dim slice of 5 window rows (O,G) + pm/pg row t
  int rb = t - 2; if (rb < 0) rb = 0;  // left-edge shift (valid rows packed front)
  float2 wv[5], gv[5];
#pragma unroll
  for (int j = 0; j < 5; j++) {
    int slot = (rb + j) & 7;
    wv[j] = *(const float2*)(ring + (size_t)(0 * 8 + slot) * Dq + based);
    gv[j] = *(const float2*)(ring + (size_t)(1 * 8 + slot) * Dq + based);
  }
  float2 pm = *(const float2*)(ring + (size_t)(2 * 8 + (t & 7)) * Dq + based);
  float2 pg = *(const float2*)(ring + (size_t)(3 * 8 + (t & 7)) * Dq + based);

  // C: partial scores over this wave's 128 dims
  const float scale = 0.04419417382415922f;  // 1/sqrt(512)
  float sj[5];
#pragma unroll
  for (int j = 0; j < 5; j++) {
    float s = st.x * wv[j].x;
    s = fmaf(st.y, wv[j].y, s);
    sj[j] = wave_sum_bcast(s);
  }
  sj[0] *= scale; sj[1] *= scale; sj[2] *= scale;
  sj[3] *= scale * m3; sj[4] *= scale * m4;

  // D: publish partials (5 lanes write red[t&1][j][wave])
  float pv = sj[0];
  pv = (lane == 1) ? sj[1] : pv;
  pv = (lane == 2) ? sj[2] : pv;
  pv = (lane == 3) ? sj[3] : pv;
  pv = (lane == 4) ? sj[4] : pv;
  if (lane < 5) red[t & 1][lane][ms] = pv;

  // E: counted vmcnt (publish rows <= t+3) + LDS drain + raw barrier
  asm volatile("s_waitcnt vmcnt(6) lgkmcnt(0)" ::: "memory");
  __builtin_amdgcn_sched_barrier(0);
  __builtin_amdgcn_s_barrier();
  __builtin_amdgcn_sched_barrier(0);

  // F: full scores (broadcast reads), softmax
  float fs[5];
#pragma unroll
  for (int j = 0; j < 5; j++) {
    float4 rv = *(const float4*)(&red[t & 1][j][0]);
    fs[j] = (rv.x + rv.y) + (rv.z + rv.w);
  }
  float mx = fmaxf(fmaxf(fmaxf(fs[0], fs[1]), fmaxf(fs[2], fs[3])), fs[4]);
  float e0 = __expf(fs[0] - mx), e1 = __expf(fs[1] - mx), e2 = __expf(fs[2] - mx);
  float e3 = __expf(fs[3] - mx), e4 = __expf(fs[4] - mx);
  float inv = __fdividef(1.0f, e0 + e1 + e2 + e3 + e4);
  float q0 = e0 * inv, q1 = e1 * inv, q2 = e2 * inv;
  float q3 = e3 * inv * m3, q4 = e4 * inv * m4;

  // G: weighted sums, gate, state update (this wave's 2 dims)
  float ax = q0 * wv[0].x; ax = fmaf(q1, wv[1].x, ax); ax = fmaf(q2, wv[2].x, ax);
  ax = fmaf(q3, wv[3].x, ax); ax = fmaf(q4, wv[4].x, ax);
  float ay = q0 * wv[0].y; ay = fmaf(q1, wv[1].y, ay); ay = fmaf(q2, wv[2].y, ay);
  ay = fmaf(q3, wv[3].y, ay); ay = fmaf(q4, wv[4].y, ay);
  float gx = q0 * gv[0].x; gx = fmaf(q1, gv[1].x, gx); gx = fmaf(q2, gv[2].x, gx);
  gx = fmaf(q3, gv[3].x, gx); gx = fmaf(q4, gv[4].x, gx);
  float gy = q0 * gv[0].y; gy = fmaf(q1, gv[1].y, gy); gy = fmaf(q2, gv[2].y, gy);
  gy = fmaf(q3, gv[3].y, gy); gy = fmaf(q4, gv[4].y, gy);
  float2 ot;
  ot.x = fmaf(ax, __fdividef(1.f, 1.f + __expf(-(pg.x + gx))), pm.x);
  ot.y = fmaf(ay, __fdividef(1.f, 1.f + __expf(-(pg.y + gy))), pm.y);
  st = ot;

  // H: rotate into output slot (static) + store my slice of row t
  float2& os = (OSLOT == 0) ? o0 : (OSLOT == 1) ? o1 : (OSLOT == 2) ? o2 : o3;
  os = ot;
  *(float2*)(po + (size_t)t * Dq + based) = os;
}

// ---------------------------------------------------------------------------
// Sequential scan: one block (4 waves) per batch. 8 blocks total.
// Wave w DMAs stream w (0:O windows, 1:G, 2:PRE_mlp, 3:PRE_gate) and owns
// output dims [128w, 128w+128).
// ---------------------------------------------------------------------------
__global__ __launch_bounds__(256, 1) void scan_kernel(
    const float* __restrict__ O, const float* __restrict__ Gm,
    const float* __restrict__ Pg, const float* __restrict__ Pm,
    float* __restrict__ out) {
  __shared__ float ring[4 * 8 * Dq];  // 64 KiB DMA rings
  __shared__ float red[2][5][4];      // score partials [buf][j][wave]

  int b = blockIdx.x;
  int tid = threadIdx.x;
  int ms = tid >> 6;        // wave id = my DMA stream
  int lane = tid & 63;
  int based = ms * 128 + lane * 2;  // my 2-dim slice offset within a row

  const float* ob  = O  + (size_t)b * Tq * Dq;
  const float* Gb  = Gm + (size_t)b * Tq * Dq;
  const float* Pgb = Pg + (size_t)b * Tq * Dq;
  const float* pmb = Pm + (size_t)b * Tq * Dq;
  float* po = out + (size_t)b * Tq * Dq;
  const float* sb = (ms == 0) ? ob : (ms == 1) ? Gb : (ms == 2) ? pmb : Pgb;

  // Prologue: DMA rows 0..4 of my stream, drain, publish.
#pragma unroll
  for (int r = 0; r < 5; r++) {
    const float* g = sb + (size_t)r * Dq + lane * 4;
    float* l = ring + (size_t)(ms * 8 + r) * Dq;
    dma1k(g, l);
    dma1k(g + 256, l + 256);
  }
  asm volatile("s_waitcnt vmcnt(0)" ::: "memory");
  __builtin_amdgcn_sched_barrier(0);
  __builtin_amdgcn_s_barrier();
  __builtin_amdgcn_sched_barrier(0);

  float2 st = make_float2(0.f, 0.f);
  float2 o0 = st, o1 = st, o2 = st, o3 = st;

  // t=0: valid window rows {0,1,2} at j=0..2.  t=1: rows {0..3} at j=0..3.
  sstep<0>(0, 0.f, 0.f, lane, ms, based, sb, po, ring, red, st, o0, o1, o2, o3);
  sstep<1>(1, 1.f, 0.f, lane, ms, based, sb, po, ring, red, st, o0, o1, o2, o3);
  // Main: t = 2..2045 (2044 steps = 511 x 4), output slot = t&3 (static).
  for (int tb = 2; tb <= 2042; tb += 4) {
    sstep<2>(tb + 0, 1.f, 1.f, lane, ms, based, sb, po, ring, red, st, o0, o1, o2, o3);
    sstep<3>(tb + 1, 1.f, 1.f, lane, ms, based, sb, po, ring, red, st, o0, o1, o2, o3);
    sstep<0>(tb + 2, 1.f, 1.f, lane, ms, based, sb, po, ring, red, st, o0, o1, o2, o3);
    sstep<1>(tb + 3, 1.f, 1.f, lane, ms, based, sb, po, ring, red, st, o0, o1, o2, o3);
  }
  // Tail: t=2046 (j=4 invalid), t=2047 (j=3,4 invalid).
  sstep<2>(2046, 1.f, 0.f, lane, ms, based, sb, po, ring, red, st, o0, o1, o2, o3);
  sstep<3>(2047, 0.f, 0.f, lane, ms, based, sb, po, ring, red, st, o0, o1, o2, o3);
}

// ---------------------------------------------------------------------------
// Precompute GEMMs (unchanged): f32, 128x128x16 tiles, 8x8 microtile.
// mode 0: windowed-A GEMM (K=2560), n<512 -> PRE_mlp(+b_mlp) into Pm,
//         n>=512 -> PRE_gate(+b_gate). mode 1: G = O @ W_gate[:,2560:].T.
// ---------------------------------------------------------------------------
__global__ __launch_bounds__(256) void gemm_pre(
    const float* __restrict__ O, const float* __restrict__ Wm,
    const float* __restrict__ Wg, const float* __restrict__ bm,
    const float* __restrict__ bg, float* __restrict__ Pm,
    float* __restrict__ Pg, float* __restrict__ Gm, int mode) {
  const int BM = 128, BN = 128, BK = 16;
  __shared__ float As[BK][132];
  __shared__ float Bs[BK][132];

  int tidx = threadIdx.x;
  int bt0 = blockIdx.x * BM;
  int b = bt0 / Tq;
  int t0 = bt0 % Tq;
  int n0 = blockIdx.y * BN;
  int K = mode ? Dq : 5 * Dq;

  int tx = tidx % 16;
  int ty = tidx / 16;
  int lr = tidx >> 2;
  int lc = (tidx & 3) * 4;

  float acc[8][8];
#pragma unroll
  for (int i = 0; i < 8; i++)
#pragma unroll
    for (int j = 0; j < 8; j++) acc[i][j] = 0.f;

  for (int kb = 0; kb < K; kb += BK) {
#pragma unroll
    for (int h = 0; h < 2; h++) {
      int m = lr + h * 64;
      int t = t0 + m;
      float4 av;
      if (mode == 0) {
        int j = kb >> 9;
        int kcol = (kb & 511) + lc;
        int sh = 2 - t; if (sh < 0) sh = 0;
        int r = t - 2 + j + sh;
        int hi = t + 2; if (hi > Tq - 1) hi = Tq - 1;
        int lo = t - 2; if (lo < 0) lo = 0;
        int nv = hi - lo + 1;
        if (j < nv) {
          av = *reinterpret_cast<const float4*>(O + ((size_t)b * Tq + r) * Dq + kcol);
        } else {
          av = make_float4(0.f, 0.f, 0.f, 0.f);
        }
      } else {
        av = *reinterpret_cast<const float4*>(O + ((size_t)b * Tq + t) * Dq + kb + lc);
      }
      As[lc + 0][m] = av.x; As[lc + 1][m] = av.y;
      As[lc + 2][m] = av.z; As[lc + 3][m] = av.w;
    }
#pragma unroll
    for (int h = 0; h < 2; h++) {
      int n = lr + h * 64;
      int gn = n0 + n;
      const float* wrow;
      int col;
      if (mode == 0) {
        if (gn < 512) { wrow = Wm + (size_t)gn * 2560; col = kb + lc; }
        else          { wrow = Wg + (size_t)(gn - 512) * 3072; col = kb + lc; }
      } else {
        wrow = Wg + (size_t)gn * 3072; col = 2560 + kb + lc;
      }
      float4 bv = *reinterpret_cast<const float4*>(wrow + col);
      Bs[lc + 0][n] = bv.x; Bs[lc + 1][n] = bv.y;
      Bs[lc + 2][n] = bv.z; Bs[lc + 3][n] = bv.w;
    }
    __syncthreads();
#pragma unroll
    for (int kk = 0; kk < BK; kk++) {
      float a[8], bb[8];
      float4 a0 = *reinterpret_cast<float4*>(&As[kk][ty * 8]);
      float4 a1 = *reinterpret_cast<float4*>(&As[kk][ty * 8 + 4]);
      float4 b0 = *reinterpret_cast<float4*>(&Bs[kk][tx * 8]);
      float4 b1 = *reinterpret_cast<float4*>(&Bs[kk][tx * 8 + 4]);
      a[0]=a0.x; a[1]=a0.y; a[2]=a0.z; a[3]=a0.w; a[4]=a1.x; a[5]=a1.y; a[6]=a1.z; a[7]=a1.w;
      bb[0]=b0.x; bb[1]=b0.y; bb[2]=b0.z; bb[3]=b0.w; bb[4]=b1.x; bb[5]=b1.y; bb[6]=b1.z; bb[7]=b1.w;
#pragma unroll
      for (int i = 0; i < 8; i++)
#pragma unroll
        for (int j = 0; j < 8; j++) acc[i][j] = fmaf(a[i], bb[j], acc[i][j]);
    }
    __syncthreads();
  }

  int gn = n0 + tx * 8;
  float bias[8];
  float* dstbase;
  int coloff;
  if (mode == 0) {
    if (gn < 512) {
#pragma unroll
      for (int j = 0; j < 8; j++) bias[j] = bm[gn + j];
      dstbase = Pm; coloff = gn;
    } else {
#pragma unroll
      for (int j = 0; j < 8; j++) bias[j] = bg[gn - 512 + j];
      dstbase = Pg; coloff = gn - 512;
    }
  } else {
#pragma unroll
    for (int j = 0; j < 8; j++) bias[j] = 0.f;
    dstbase = Gm; coloff = gn;
  }
#pragma unroll
  for (int i = 0; i < 8; i++) {
    int bt = bt0 + ty * 8 + i;
    float4 v0 = make_float4(acc[i][0] + bias[0], acc[i][1] + bias[1],
                            acc[i][2] + bias[2], acc[i][3] + bias[3]);
    float4 v1 = make_float4(acc[i][4] + bias[4], acc[i][5] + bias[5],
                            acc[i][6] + bias[6], acc[i][7] + bias[7]);
    float4* d = reinterpret_cast<float4*>(dstbase + (size_t)bt * Dq + coloff);
    d[0] = v0;
    d[1] = v1;
  }
}

extern "C" void kernel_launch(void* const* d_in, const int* in_sizes, int n_in,
                              void* d_out, int out_size, void* d_ws, size_t ws_size,
                              hipStream_t stream) {
  const float* O  = (const float*)d_in[0];  // outputs [8,2048,512]
  const float* Wm = (const float*)d_in[1];  // W_mlp [512,2560]
  const float* bm = (const float*)d_in[2];  // b_mlp [512]
  const float* Wg = (const float*)d_in[3];  // W_gate [512,3072]
  const float* bg = (const float*)d_in[4];  // b_gate [512]
  float* out = (float*)d_out;               // [8,2048,512]

  const size_t NTOT = (size_t)Bq * Tq * Dq;  // 8.39M elements
  float* Pg = (float*)d_ws;                  // PRE_gate [8,2048,512]
  float* Gm = Pg + NTOT;                     // G        [8,2048,512]
  bool sep = ws_size >= (size_t)3 * NTOT * sizeof(float);
  float* Pm = sep ? (Gm + NTOT) : out;       // PRE_mlp (sep buffer if ws allows)

  gemm_pre<<<dim3(128, 8), dim3(256), 0, stream>>>(O, Wm, Wg, bm, bg, Pm, Pg, Gm, 0);
  gemm_pre<<<dim3(128, 4), dim3(256), 0, stream>>>(O, Wm, Wg, bm, bg, Pm, Pg, Gm, 1);

  scan_kernel<<<dim3(Bq), dim3(256), 0, stream>>>(O, Gm, Pg, Pm, out);
}

// Round 6
// 2998.064 us; speedup vs baseline: 1.0552x; 1.0552x over previous
//
#include <hip/hip_runtime.h>

#define Bq 8
#define Tq 2048
#define Dq 512

typedef const __attribute__((address_space(1))) void* gas_t;
typedef __attribute__((address_space(3))) void* las_t;

// One wave: DMA 1KB (64 lanes x 16B) global -> LDS. Per-lane global addr,
// wave-uniform LDS base (HW adds lane*16). No VGPR defs => compiler cannot
// sink/serialize it; completion tracked only by vmcnt.
__device__ __forceinline__ void dma1k(const float* g_lane, float* l_base) {
  __builtin_amdgcn_global_load_lds((gas_t)g_lane, (las_t)l_base, 16, 0, 0);
}

// DPP wave(64) sum, broadcast via readlane(63) -> SGPR.
template <int CTRL>
__device__ __forceinline__ float dppadd(float v) {
  int r = __builtin_amdgcn_update_dpp(0, __float_as_int(v), CTRL, 0xF, 0xF, true);
  return v + __int_as_float(r);
}
__device__ __forceinline__ float wave_sum_bcast(float v) {
  v = dppadd<0x111>(v);  // row_shr:1
  v = dppadd<0x112>(v);  // row_shr:2
  v = dppadd<0x114>(v);  // row_shr:4
  v = dppadd<0x118>(v);  // row_shr:8
  v = dppadd<0x142>(v);  // row_bcast:15
  v = dppadd<0x143>(v);  // row_bcast:31
  return __int_as_float(__builtin_amdgcn_readlane(__float_as_int(v), 63));
}

__device__ __forceinline__ float dot8(const float4& xa, const float4& xb,
                                      const float4& ya, const float4& yb) {
  float s = xa.x * ya.x;
  s = fmaf(xa.y, ya.y, s); s = fmaf(xa.z, ya.z, s); s = fmaf(xa.w, ya.w, s);
  s = fmaf(xb.x, yb.x, s); s = fmaf(xb.y, yb.y, s);
  s = fmaf(xb.z, yb.z, s); s = fmaf(xb.w, yb.w, s);
  return s;
}

#define WSUM4(dst, arr)                                                        \
  dst.x = q0 * arr[0].x + q1 * arr[1].x + q2 * arr[2].x + q3 * arr[3].x +      \
          q4 * arr[4].x;                                                       \
  dst.y = q0 * arr[0].y + q1 * arr[1].y + q2 * arr[2].y + q3 * arr[3].y +      \
          q4 * arr[4].y;                                                       \
  dst.z = q0 * arr[0].z + q1 * arr[1].z + q2 * arr[2].z + q3 * arr[3].z +      \
          q4 * arr[4].z;                                                       \
  dst.w = q0 * arr[0].w + q1 * arr[1].w + q2 * arr[2].w + q3 * arr[3].w +      \
          q4 * arr[4].w;

// ---------------------------------------------------------------------------
// One scan step, single wave, barrier-free.
// LDS rings: stream s (0:O,1:G,2:Pm,3:Pg), 8 row slots (slot = row&7), 2KB/row.
// Per-step VMEM issue order: [8 DMA (row t+5)] [vmcnt(30)] [...] [2 stores].
// 10 VMEM ops/step => vmcnt(30) retires everything older than {t's 8 DMAs +
// t-1's 10 + t-2's 10 + 2 of t-3} = all DMAs of step t-3 (row t+2) and older:
// exactly what this step's ds_reads need, with ~3 steps of latency lead.
// Window reads: rb=max(0,t-2), rows rb..rb+4 at j=0..4; edge-invalid j are
// masked (score forced to exact 0, matching reference zero-padding; they keep
// exp(0) in the softmax denominator; garbage slots are finite -> 0*x safe).
// OSLOT: 4-deep output register rotation => the compiler's WAR wait on store
// sources is vmcnt(~38), strictly weaker than our vmcnt(30) => a no-op.
// ---------------------------------------------------------------------------
template <int OSLOT>
__device__ __forceinline__ void sstep(
    int t, int lane,
    const float* __restrict__ ob, const float* __restrict__ Gb,
    const float* __restrict__ pmb, const float* __restrict__ pgb,
    float* __restrict__ po, float* __restrict__ ring,
    float4& stA, float4& stB,
    float4& oA0, float4& oB0, float4& oA1, float4& oB1,
    float4& oA2, float4& oB2, float4& oA3, float4& oB3) {
  // ---- A: DMA row t+5 for all 4 streams into slot (row&7) ----
  int r5 = t + 5; if (r5 > Tq - 1) r5 = Tq - 1;
  {
    int sl5 = r5 & 7;
    size_t go = (size_t)r5 * Dq + lane * 4;
    dma1k(ob  + go, ring + (size_t)(0 * 8 + sl5) * Dq);
    dma1k(ob  + go + 256, ring + (size_t)(0 * 8 + sl5) * Dq + 256);
    dma1k(Gb  + go, ring + (size_t)(1 * 8 + sl5) * Dq);
    dma1k(Gb  + go + 256, ring + (size_t)(1 * 8 + sl5) * Dq + 256);
    dma1k(pmb + go, ring + (size_t)(2 * 8 + sl5) * Dq);
    dma1k(pmb + go + 256, ring + (size_t)(2 * 8 + sl5) * Dq + 256);
    dma1k(pgb + go, ring + (size_t)(3 * 8 + sl5) * Dq);
    dma1k(pgb + go + 256, ring + (size_t)(3 * 8 + sl5) * Dq + 256);
  }
  // ---- B: counted wait — row t+2 (and older) now resident in LDS ----
  asm volatile("s_waitcnt vmcnt(30)" ::: "memory");
  __builtin_amdgcn_sched_barrier(0);

  // ---- C: ds_read 5 window rows (O,G) + pm/pg row t (my 8-dim slice) ----
  int rb = t - 2; if (rb < 0) rb = 0;
  int lo = lane * 4;
  float4 wA[5], wB[5], gA[5], gB[5];
#pragma unroll
  for (int j = 0; j < 5; j++) {
    int sl = (rb + j) & 7;
    const float* pw = ring + (size_t)(0 * 8 + sl) * Dq + lo;
    wA[j] = *(const float4*)pw;
    wB[j] = *(const float4*)(pw + 256);
    const float* pgv = ring + (size_t)(1 * 8 + sl) * Dq + lo;
    gA[j] = *(const float4*)pgv;
    gB[j] = *(const float4*)(pgv + 256);
  }
  int slt = t & 7;
  const float* ppm = ring + (size_t)(2 * 8 + slt) * Dq + lo;
  float4 pmA = *(const float4*)ppm;
  float4 pmB = *(const float4*)(ppm + 256);
  const float* ppg = ring + (size_t)(3 * 8 + slt) * Dq + lo;
  float4 pgA = *(const float4*)ppg;
  float4 pgB = *(const float4*)(ppg + 256);

  // ---- D: edge masks (j=0..2 always valid) ----
  float m3 = (t == 0 || t == Tq - 1) ? 0.f : 1.f;
  float m4 = (t >= 2 && t <= Tq - 3) ? 1.f : 0.f;

  // ---- E: scores + softmax ----
  const float scale = 0.04419417382415922f;  // 1/sqrt(512)
  float s0 = wave_sum_bcast(dot8(stA, stB, wA[0], wB[0])) * scale;
  float s1 = wave_sum_bcast(dot8(stA, stB, wA[1], wB[1])) * scale;
  float s2 = wave_sum_bcast(dot8(stA, stB, wA[2], wB[2])) * scale;
  float s3 = wave_sum_bcast(dot8(stA, stB, wA[3], wB[3])) * (scale * m3);
  float s4 = wave_sum_bcast(dot8(stA, stB, wA[4], wB[4])) * (scale * m4);
  float mx = fmaxf(fmaxf(fmaxf(s0, s1), fmaxf(s2, s3)), s4);
  float e0 = __expf(s0 - mx), e1 = __expf(s1 - mx), e2 = __expf(s2 - mx);
  float e3 = __expf(s3 - mx), e4 = __expf(s4 - mx);
  float inv = __fdividef(1.0f, e0 + e1 + e2 + e3 + e4);
  float q0 = e0 * inv, q1 = e1 * inv, q2 = e2 * inv;
  float q3 = e3 * inv * m3, q4 = e4 * inv * m4;  // padded rows contribute 0

  // ---- F: weighted sums, gate, output, state ----
  float4 atA, atB, gsA, gsB;
  WSUM4(atA, wA); WSUM4(atB, wB); WSUM4(gsA, gA); WSUM4(gsB, gB);
  float4 otA, otB;
  otA.x = fmaf(atA.x, __fdividef(1.f, 1.f + __expf(-(pgA.x + gsA.x))), pmA.x);
  otA.y = fmaf(atA.y, __fdividef(1.f, 1.f + __expf(-(pgA.y + gsA.y))), pmA.y);
  otA.z = fmaf(atA.z, __fdividef(1.f, 1.f + __expf(-(pgA.z + gsA.z))), pmA.z);
  otA.w = fmaf(atA.w, __fdividef(1.f, 1.f + __expf(-(pgA.w + gsA.w))), pmA.w);
  otB.x = fmaf(atB.x, __fdividef(1.f, 1.f + __expf(-(pgB.x + gsB.x))), pmB.x);
  otB.y = fmaf(atB.y, __fdividef(1.f, 1.f + __expf(-(pgB.y + gsB.y))), pmB.y);
  otB.z = fmaf(atB.z, __fdividef(1.f, 1.f + __expf(-(pgB.z + gsB.z))), pmB.z);
  otB.w = fmaf(atB.w, __fdividef(1.f, 1.f + __expf(-(pgB.w + gsB.w))), pmB.w);
  stA = otA; stB = otB;

  // ---- G: rotate into output slot (static) + store row t ----
  float4& osA = (OSLOT == 0) ? oA0 : (OSLOT == 1) ? oA1 : (OSLOT == 2) ? oA2 : oA3;
  float4& osB = (OSLOT == 0) ? oB0 : (OSLOT == 1) ? oB1 : (OSLOT == 2) ? oB2 : oB3;
  osA = otA; osB = otB;
  float* dst = po + (size_t)t * Dq + lo;
  *reinterpret_cast<float4*>(dst) = osA;
  *reinterpret_cast<float4*>(dst + 256) = osB;
}

// ---------------------------------------------------------------------------
// Sequential scan: ONE WAVE per batch (8 blocks x 64 threads). Barrier-free:
// DMA->LDS ordering is purely counted vmcnt within the wave.
// ---------------------------------------------------------------------------
__global__ __launch_bounds__(64, 1) void scan_kernel(
    const float* __restrict__ O, const float* __restrict__ Gm,
    const float* __restrict__ Pg, const float* __restrict__ Pm,
    float* __restrict__ out) {
  __shared__ float ring[4 * 8 * Dq];  // 64 KiB: 4 streams x 8 row slots x 2KB

  int b = blockIdx.x;
  int lane = threadIdx.x;
  const float* ob  = O  + (size_t)b * Tq * Dq;
  const float* Gb  = Gm + (size_t)b * Tq * Dq;
  const float* pgb = Pg + (size_t)b * Tq * Dq;
  const float* pmb = Pm + (size_t)b * Tq * Dq;
  float* po = out + (size_t)b * Tq * Dq;

  // Prologue: DMA rows 0..4, all streams (8 ops/row, stream-major per row:
  // O,O,G,G,Pm,Pm,Pg,Pg). Then retire rows 0..2 (vmcnt(16) leaves rows 3,4
  // in flight; the per-step vmcnt(30) schedule picks them up exactly when
  // first needed — verified by hand for t=0..4).
#pragma unroll
  for (int r = 0; r < 5; r++) {
    size_t go = (size_t)r * Dq + lane * 4;
    dma1k(ob  + go, ring + (size_t)(0 * 8 + r) * Dq);
    dma1k(ob  + go + 256, ring + (size_t)(0 * 8 + r) * Dq + 256);
    dma1k(Gb  + go, ring + (size_t)(1 * 8 + r) * Dq);
    dma1k(Gb  + go + 256, ring + (size_t)(1 * 8 + r) * Dq + 256);
    dma1k(pmb + go, ring + (size_t)(2 * 8 + r) * Dq);
    dma1k(pmb + go + 256, ring + (size_t)(2 * 8 + r) * Dq + 256);
    dma1k(pgb + go, ring + (size_t)(3 * 8 + r) * Dq);
    dma1k(pgb + go + 256, ring + (size_t)(3 * 8 + r) * Dq + 256);
  }
  asm volatile("s_waitcnt vmcnt(16)" ::: "memory");
  __builtin_amdgcn_sched_barrier(0);

  float4 z = make_float4(0.f, 0.f, 0.f, 0.f);
  float4 stA = z, stB = z;
  float4 oA0 = z, oB0 = z, oA1 = z, oB1 = z;
  float4 oA2 = z, oB2 = z, oA3 = z, oB3 = z;

  // 2048 steps = 512 x 4-phase (output rotation is the only static phasing).
  for (int tb = 0; tb < Tq; tb += 4) {
    sstep<0>(tb + 0, lane, ob, Gb, pmb, pgb, po, ring, stA, stB,
             oA0, oB0, oA1, oB1, oA2, oB2, oA3, oB3);
    sstep<1>(tb + 1, lane, ob, Gb, pmb, pgb, po, ring, stA, stB,
             oA0, oB0, oA1, oB1, oA2, oB2, oA3, oB3);
    sstep<2>(tb + 2, lane, ob, Gb, pmb, pgb, po, ring, stA, stB,
             oA0, oB0, oA1, oB1, oA2, oB2, oA3, oB3);
    sstep<3>(tb + 3, lane, ob, Gb, pmb, pgb, po, ring, stA, stB,
             oA0, oB0, oA1, oB1, oA2, oB2, oA3, oB3);
  }
}

// ---------------------------------------------------------------------------
// Precompute GEMMs (unchanged): f32, 128x128x16 tiles, 8x8 microtile.
// mode 0: windowed-A GEMM (K=2560), n<512 -> PRE_mlp(+b_mlp) into Pm,
//         n>=512 -> PRE_gate(+b_gate). mode 1: G = O @ W_gate[:,2560:].T.
// ---------------------------------------------------------------------------
__global__ __launch_bounds__(256) void gemm_pre(
    const float* __restrict__ O, const float* __restrict__ Wm,
    const float* __restrict__ Wg, const float* __restrict__ bm,
    const float* __restrict__ bg, float* __restrict__ Pm,
    float* __restrict__ Pg, float* __restrict__ Gm, int mode) {
  const int BM = 128, BN = 128, BK = 16;
  __shared__ float As[BK][132];
  __shared__ float Bs[BK][132];

  int tidx = threadIdx.x;
  int bt0 = blockIdx.x * BM;
  int b = bt0 / Tq;
  int t0 = bt0 % Tq;
  int n0 = blockIdx.y * BN;
  int K = mode ? Dq : 5 * Dq;

  int tx = tidx % 16;
  int ty = tidx / 16;
  int lr = tidx >> 2;
  int lc = (tidx & 3) * 4;

  float acc[8][8];
#pragma unroll
  for (int i = 0; i < 8; i++)
#pragma unroll
    for (int j = 0; j < 8; j++) acc[i][j] = 0.f;

  for (int kb = 0; kb < K; kb += BK) {
#pragma unroll
    for (int h = 0; h < 2; h++) {
      int m = lr + h * 64;
      int t = t0 + m;
      float4 av;
      if (mode == 0) {
        int j = kb >> 9;
        int kcol = (kb & 511) + lc;
        int sh = 2 - t; if (sh < 0) sh = 0;
        int r = t - 2 + j + sh;
        int hi = t + 2; if (hi > Tq - 1) hi = Tq - 1;
        int lo2 = t - 2; if (lo2 < 0) lo2 = 0;
        int nv = hi - lo2 + 1;
        if (j < nv) {
          av = *reinterpret_cast<const float4*>(O + ((size_t)b * Tq + r) * Dq + kcol);
        } else {
          av = make_float4(0.f, 0.f, 0.f, 0.f);
        }
      } else {
        av = *reinterpret_cast<const float4*>(O + ((size_t)b * Tq + t) * Dq + kb + lc);
      }
      As[lc + 0][m] = av.x; As[lc + 1][m] = av.y;
      As[lc + 2][m] = av.z; As[lc + 3][m] = av.w;
    }
#pragma unroll
    for (int h = 0; h < 2; h++) {
      int n = lr + h * 64;
      int gn = n0 + n;
      const float* wrow;
      int col;
      if (mode == 0) {
        if (gn < 512) { wrow = Wm + (size_t)gn * 2560; col = kb + lc; }
        else          { wrow = Wg + (size_t)(gn - 512) * 3072; col = kb + lc; }
      } else {
        wrow = Wg + (size_t)gn * 3072; col = 2560 + kb + lc;
      }
      float4 bv = *reinterpret_cast<const float4*>(wrow + col);
      Bs[lc + 0][n] = bv.x; Bs[lc + 1][n] = bv.y;
      Bs[lc + 2][n] = bv.z; Bs[lc + 3][n] = bv.w;
    }
    __syncthreads();
#pragma unroll
    for (int kk = 0; kk < BK; kk++) {
      float a[8], bb[8];
      float4 a0 = *reinterpret_cast<float4*>(&As[kk][ty * 8]);
      float4 a1 = *reinterpret_cast<float4*>(&As[kk][ty * 8 + 4]);
      float4 b0 = *reinterpret_cast<float4*>(&Bs[kk][tx * 8]);
      float4 b1 = *reinterpret_cast<float4*>(&Bs[kk][tx * 8 + 4]);
      a[0]=a0.x; a[1]=a0.y; a[2]=a0.z; a[3]=a0.w; a[4]=a1.x; a[5]=a1.y; a[6]=a1.z; a[7]=a1.w;
      bb[0]=b0.x; bb[1]=b0.y; bb[2]=b0.z; bb[3]=b0.w; bb[4]=b1.x; bb[5]=b1.y; bb[6]=b1.z; bb[7]=b1.w;
#pragma unroll
      for (int i = 0; i < 8; i++)
#pragma unroll
        for (int j = 0; j < 8; j++) acc[i][j] = fmaf(a[i], bb[j], acc[i][j]);
    }
    __syncthreads();
  }

  int gn = n0 + tx * 8;
  float bias[8];
  float* dstbase;
  int coloff;
  if (mode == 0) {
    if (gn < 512) {
#pragma unroll
      for (int j = 0; j < 8; j++) bias[j] = bm[gn + j];
      dstbase = Pm; coloff = gn;
    } else {
#pragma unroll
      for (int j = 0; j < 8; j++) bias[j] = bg[gn - 512 + j];
      dstbase = Pg; coloff = gn - 512;
    }
  } else {
#pragma unroll
    for (int j = 0; j < 8; j++) bias[j] = 0.f;
    dstbase = Gm; coloff = gn;
  }
#pragma unroll
  for (int i = 0; i < 8; i++) {
    int bt = bt0 + ty * 8 + i;
    float4 v0 = make_float4(acc[i][0] + bias[0], acc[i][1] + bias[1],
                            acc[i][2] + bias[2], acc[i][3] + bias[3]);
    float4 v1 = make_float4(acc[i][4] + bias[4], acc[i][5] + bias[5],
                            acc[i][6] + bias[6], acc[i][7] + bias[7]);
    float4* d = reinterpret_cast<float4*>(dstbase + (size_t)bt * Dq + coloff);
    d[0] = v0;
    d[1] = v1;
  }
}

extern "C" void kernel_launch(void* const* d_in, const int* in_sizes, int n_in,
                              void* d_out, int out_size, void* d_ws, size_t ws_size,
                              hipStream_t stream) {
  const float* O  = (const float*)d_in[0];  // outputs [8,2048,512]
  const float* Wm = (const float*)d_in[1];  // W_mlp [512,2560]
  const float* bm = (const float*)d_in[2];  // b_mlp [512]
  const float* Wg = (const float*)d_in[3];  // W_gate [512,3072]
  const float* bg = (const float*)d_in[4];  // b_gate [512]
  float* out = (float*)d_out;               // [8,2048,512]

  const size_t NTOT = (size_t)Bq * Tq * Dq;  // 8.39M elements
  float* Pg = (float*)d_ws;                  // PRE_gate [8,2048,512]
  float* Gm = Pg + NTOT;                     // G        [8,2048,512]
  bool sep = ws_size >= (size_t)3 * NTOT * sizeof(float);
  float* Pm = sep ? (Gm + NTOT) : out;       // PRE_mlp (sep buffer if ws allows)

  gemm_pre<<<dim3(128, 8), dim3(256), 0, stream>>>(O, Wm, Wg, bm, bg, Pm, Pg, Gm, 0);
  gemm_pre<<<dim3(128, 4), dim3(256), 0, stream>>>(O, Wm, Wg, bm, bg, Pm, Pg, Gm, 1);

  scan_kernel<<<dim3(Bq), dim3(64), 0, stream>>>(O, Gm, Pg, Pm, out);
}